// Round 10
// baseline (6947.362 us; speedup 1.0000x reference)
//
#include <hip/hip_runtime.h>
#include <math.h>

#define B_SZ 32
#define T_SZ 2048
#define DIN 256
#define DH 256
#define FOUR_D 1024

// G=4 batches per group; 16 WGs per group (each owns 16 dims); 512 thr/WG.
#define GB 4           // batches per group
#define NW 16          // WGs per group
#define DPW 16         // dims per WG
#define COLS 64        // preact cols per WG (4 gates x 16 dims)
#define KSEG 8         // 512 threads = 64 cols x 8 K-segments
#define KLEN 32        // K elements per segment

__global__ void zero_ws(unsigned int* p, int n) {
    int i = blockIdx.x * blockDim.x + threadIdx.x;
    if (i < n) p[i] = 0u;
}

// px[r][f] = bias[f] + sum_k x_row(r)[k] * W[k][f];  r = tt*32 + b   (proven)
__global__ __launch_bounds__(256) void px_gemm(
    const float* __restrict__ x, const float* __restrict__ W,
    const float* __restrict__ bias, float* __restrict__ px,
    int t0)
{
    __shared__ float xt[16][DIN];
    const int tid = threadIdx.x;
    const int rbase = blockIdx.x * 16;

    {
        int row = tid >> 4;
        int seg = (tid & 15) * 16;
        int r = rbase + row;
        int bb = r & 31;
        int tt = r >> 5;
        const float4* s4 = (const float4*)(x + ((size_t)bb * T_SZ + (size_t)(t0 + tt)) * DIN + seg);
        float4* dst = (float4*)&xt[row][seg];
        dst[0] = s4[0]; dst[1] = s4[1]; dst[2] = s4[2]; dst[3] = s4[3];
    }
    __syncthreads();

    const int j = tid * 4;
    float4 bv = *(const float4*)&bias[j];
    float acc[16][4];
#pragma unroll
    for (int r = 0; r < 16; ++r) {
        acc[r][0] = bv.x; acc[r][1] = bv.y; acc[r][2] = bv.z; acc[r][3] = bv.w;
    }

    for (int k = 0; k < DIN; k += 4) {
        float4 w0 = *(const float4*)&W[(size_t)(k + 0) * FOUR_D + j];
        float4 w1 = *(const float4*)&W[(size_t)(k + 1) * FOUR_D + j];
        float4 w2 = *(const float4*)&W[(size_t)(k + 2) * FOUR_D + j];
        float4 w3 = *(const float4*)&W[(size_t)(k + 3) * FOUR_D + j];
#pragma unroll
        for (int r = 0; r < 16; ++r) {
            float4 xv = *(const float4*)&xt[r][k];
            acc[r][0] += xv.x * w0.x + xv.y * w1.x + xv.z * w2.x + xv.w * w3.x;
            acc[r][1] += xv.x * w0.y + xv.y * w1.y + xv.z * w2.y + xv.w * w3.y;
            acc[r][2] += xv.x * w0.z + xv.y * w1.z + xv.z * w2.z + xv.w * w3.z;
            acc[r][3] += xv.x * w0.w + xv.y * w1.w + xv.z * w2.w + xv.w * w3.w;
        }
    }

#pragma unroll
    for (int r = 0; r < 16; ++r) {
        float4 st = make_float4(acc[r][0], acc[r][1], acc[r][2], acc[r][3]);
        *(float4*)&px[((size_t)(rbase + r)) * FOUR_D + j] = st;
    }
}

// Per-step U weights: 8 quads of named scalars, loaded PRE-POLL and pinned
// (asm output can't be rematerialized; issued before the spin so the L2
// latency hides under the poll window). Each value is used by 4 adjacent
// FMAs (one per batch) -> even a spill caps the re-stream at 1x per step.
#define REP8(M) M(0) M(1) M(2) M(3) M(4) M(5) M(6) M(7)

#define ULOAD(n)                                                     \
    float u##n##0 = Ucol[(size_t)(kbase + 4*(n) + 0) * FOUR_D];      \
    float u##n##1 = Ucol[(size_t)(kbase + 4*(n) + 1) * FOUR_D];      \
    float u##n##2 = Ucol[(size_t)(kbase + 4*(n) + 2) * FOUR_D];      \
    float u##n##3 = Ucol[(size_t)(kbase + 4*(n) + 3) * FOUR_D];      \
    asm volatile("" : "+v"(u##n##0), "+v"(u##n##1),                  \
                      "+v"(u##n##2), "+v"(u##n##3));

#define GSTEP(n) {                                                   \
    float4 h0 = *(const float4*)&h_lds[0][kbase + 4*(n)];            \
    float4 h1 = *(const float4*)&h_lds[1][kbase + 4*(n)];            \
    float4 h2 = *(const float4*)&h_lds[2][kbase + 4*(n)];            \
    float4 h3 = *(const float4*)&h_lds[3][kbase + 4*(n)];            \
    a0 += h0.x*u##n##0 + h0.y*u##n##1 + h0.z*u##n##2 + h0.w*u##n##3; \
    a1 += h1.x*u##n##0 + h1.y*u##n##1 + h1.z*u##n##2 + h1.w*u##n##3; \
    a2 += h2.x*u##n##0 + h2.y*u##n##1 + h2.z*u##n##2 + h2.w*u##n##3; \
    a3 += h3.x*u##n##0 + h3.y*u##n##1 + h3.z*u##n##2 + h3.w*u##n##3; }

// Group-batched transposed scan: blockIdx = group*16 + w; group owns batches
// 4*group..4*group+3; WG owns dims [16w,16w+16) for ALL 4 batches. U weights
// streamed once per step (amortized over 4 batches). h exchange: proven
// agent-scope 64-bit tagged atomics, parity double-buffered.
__global__ __launch_bounds__(512, 2) void lstm_scan8(
    const float* __restrict__ px, const float* __restrict__ U,
    float* __restrict__ out, unsigned long long* __restrict__ hbuf,
    float* __restrict__ cstate, int t0, int ct)
{
    __shared__ float h_lds[GB][DH];
    __shared__ float red[KSEG][GB][COLS + 1];
    __shared__ float act_s[GB][COLS + 1];

    const int grp = blockIdx.x >> 4;   // batch group 0..7
    const int w = blockIdx.x & 15;     // WG-within-group
    const int bg = grp * GB;           // first batch of group
    const int tid = threadIdx.x;
    const int c = tid & (COLS - 1);    // col within WG: 0..63
    const int kseg = tid >> 6;         // 0..7
    const int kbase = kseg << 5;       // 0,32,...,224
    const int gate = c >> 4, jj = c & 15;
    const int colg = (gate << 8) + (w << 4) + jj;   // global preact column
    const float* Ucol = U + colg;

    // cell state: threads 0..63 hold (g = tid>>4, dd = tid&15)
    float c_reg = 0.0f;
    if (tid < GB * DPW) {
        int g = tid >> 4, dd = tid & 15;
        c_reg = cstate[(bg + g) * DH + (w << 4) + dd];
    }

    // poll assignment: thread handles (g2, dim) and (g2+2, dim)
    const int pdim = tid & 255;
    const int g2 = tid >> 8;           // 0..1

    for (int tt = 0; tt < ct; ++tt) {
        const int s = t0 + tt + 1;     // computing h_s from h_{s-1}

        // --- pre-poll: issue per-step weight loads (pinned) + px prefetch
        REP8(ULOAD)
        float pxv = 0.0f;
        if (tid < GB * COLS) {         // 256 threads: g = tid>>6, col = tid&63
            int g = tid >> 6, cc = tid & 63;
            int cg = ((cc >> 4) << 8) + (w << 4) + (cc & 15);
            pxv = px[((size_t)tt * B_SZ + bg + g) * FOUR_D + cg];
        }

        // --- acquire h_{s-1} for 4 batches: dual-slot combined spin
        if (s == 1) {
            h_lds[g2][pdim] = 0.0f;
            h_lds[g2 + 2][pdim] = 0.0f;
        } else {
            const unsigned long long want = (unsigned long long)(unsigned)(s - 1);
            const size_t base = ((size_t)((s - 1) & 1) * B_SZ) * DH;
            const unsigned long long* slotA = hbuf + base + (bg + g2) * DH + pdim;
            const unsigned long long* slotB = hbuf + base + (bg + g2 + 2) * DH + pdim;
            bool dA = false, dB = false;
            do {
                if (!dA) {
                    unsigned long long v = __hip_atomic_load(slotA, __ATOMIC_RELAXED,
                                                             __HIP_MEMORY_SCOPE_AGENT);
                    if ((v >> 32) == want) { h_lds[g2][pdim] = __uint_as_float((unsigned)v); dA = true; }
                }
                if (!dB) {
                    unsigned long long v = __hip_atomic_load(slotB, __ATOMIC_RELAXED,
                                                             __HIP_MEMORY_SCOPE_AGENT);
                    if ((v >> 32) == want) { h_lds[g2 + 2][pdim] = __uint_as_float((unsigned)v); dB = true; }
                }
            } while (!(dA && dB));
        }
        __syncthreads();   // B1: h_lds ready (all 4 batches)

        // --- GEMV: 128 FMAs (32 k x 4 batches), weights from pinned regs
        float a0 = 0.f, a1 = 0.f, a2 = 0.f, a3 = 0.f;
        REP8(GSTEP)
        red[kseg][0][c] = a0;
        red[kseg][1][c] = a1;
        red[kseg][2][c] = a2;
        red[kseg][3][c] = a3;
        __syncthreads();   // B2: partials ready

        // --- activations: 256 threads, one preact each
        if (tid < GB * COLS) {
            int g = tid >> 6, cc = tid & 63;
            float pre = pxv;
#pragma unroll
            for (int ks = 0; ks < KSEG; ++ks) pre += red[ks][g][cc];
            float a;
            if (cc < 48) {
                a = 1.0f / (1.0f + __expf(-pre));          // i, f, o
            } else {
                float e = __expf(-2.0f * pre);             // g = tanh
                a = 2.0f / (1.0f + e) - 1.0f;
            }
            act_s[g][cc] = a;
        }
        __syncthreads();   // B3: activations ready

        // --- cell update + publish + out: 64 threads (g, dd)
        if (tid < GB * DPW) {
            int g = tid >> 4, dd = tid & 15;
            float ig = act_s[g][dd];
            float fg = act_s[g][16 + dd];
            float og = act_s[g][32 + dd];
            float gv = act_s[g][48 + dd];
            float cn = fg * c_reg + ig * gv;
            c_reg = cn;
            float ec = __expf(-2.0f * cn);
            float hn = og * (2.0f / (1.0f + ec) - 1.0f);
            const int d = (w << 4) + dd;
            unsigned long long pv =
                ((unsigned long long)(unsigned)s << 32) |
                (unsigned long long)__float_as_uint(hn);
            __hip_atomic_store(hbuf + (((size_t)(s & 1) * B_SZ + bg + g) * DH + d),
                               pv, __ATOMIC_RELAXED, __HIP_MEMORY_SCOPE_AGENT);
            out[((size_t)(bg + g) * T_SZ + (size_t)(s - 1)) * DH + d] = hn;
        }
        // no trailing barrier: next-iter h_lds writes occur only after B3_tt
        // passage (all threads), whose readers finished before B2_tt; red
        // rewrite gated behind B1_{tt+1}; act_s rewrite behind B2_{tt+1}.
    }

    if (tid < GB * DPW) {
        int g = tid >> 4, dd = tid & 15;
        cstate[(bg + g) * DH + (w << 4) + dd] = c_reg;
    }
}

extern "C" void kernel_launch(void* const* d_in, const int* in_sizes, int n_in,
                              void* d_out, int out_size, void* d_ws, size_t ws_size,
                              hipStream_t stream) {
    const float* x    = (const float*)d_in[0];
    const float* W    = (const float*)d_in[1];
    const float* U    = (const float*)d_in[2];
    const float* bias = (const float*)d_in[3];
    float* out = (float*)d_out;

    // ws layout: cstate 32KB @0 | hbuf 128KB @32K | pxbuf @160K
    float* cstate = (float*)d_ws;
    unsigned long long* hbuf = (unsigned long long*)((char*)d_ws + 32 * 1024);
    size_t px_off = 160 * 1024;
    float* pxbuf = (float*)((char*)d_ws + px_off);

    size_t avail = (ws_size > px_off) ? (ws_size - px_off) : 0;
    size_t per_step = (size_t)B_SZ * FOUR_D * sizeof(float);  // 128 KB
    long ct_max = (long)(avail / per_step);
    int CT = (ct_max >= T_SZ) ? T_SZ : (int)ct_max;
    if (CT < 1) CT = 1;

    // zero cstate + hbuf each launch
    int zero_words = (160 * 1024) / 4;
    zero_ws<<<(zero_words + 255) / 256, 256, 0, stream>>>((unsigned int*)d_ws, zero_words);

    for (int t0 = 0; t0 < T_SZ; t0 += CT) {
        int ct = (T_SZ - t0 < CT) ? (T_SZ - t0) : CT;
        int rows = ct * B_SZ;
        px_gemm<<<rows / 16, 256, 0, stream>>>(x, W, bias, pxbuf, t0);
        lstm_scan8<<<8 * NW, 512, 0, stream>>>(pxbuf, U, out, hbuf, cstate, t0, ct);
    }
}

// Round 11
// 4721.202 us; speedup vs baseline: 1.4715x; 1.4715x over previous
//
#include <hip/hip_runtime.h>
#include <math.h>

#define B_SZ 32
#define T_SZ 2048
#define DIN 256
#define DH 256
#define FOUR_D 1024

// scan decomposition: 8 WGs per batch, 512 threads each (R9-proven best)
#define NW 8
#define DPW 32
#define COLS 128       // preact cols per WG (4 gates x 32 dims)
#define KSEG 4         // 512 threads = 128 cols x 4 K-segments
#define KLEN 64        // K elements per segment

__global__ void zero_ws(unsigned int* p, int n) {
    int i = blockIdx.x * blockDim.x + threadIdx.x;
    if (i < n) p[i] = 0u;
}

// px[r][f] = bias[f] + sum_k x_row(r)[k] * W[k][f];  r = tt*32 + b   (proven)
__global__ __launch_bounds__(256) void px_gemm(
    const float* __restrict__ x, const float* __restrict__ W,
    const float* __restrict__ bias, float* __restrict__ px,
    int t0)
{
    __shared__ float xt[16][DIN];
    const int tid = threadIdx.x;
    const int rbase = blockIdx.x * 16;

    {
        int row = tid >> 4;
        int seg = (tid & 15) * 16;
        int r = rbase + row;
        int bb = r & 31;
        int tt = r >> 5;
        const float4* s4 = (const float4*)(x + ((size_t)bb * T_SZ + (size_t)(t0 + tt)) * DIN + seg);
        float4* dst = (float4*)&xt[row][seg];
        dst[0] = s4[0]; dst[1] = s4[1]; dst[2] = s4[2]; dst[3] = s4[3];
    }
    __syncthreads();

    const int j = tid * 4;
    float4 bv = *(const float4*)&bias[j];
    float acc[16][4];
#pragma unroll
    for (int r = 0; r < 16; ++r) {
        acc[r][0] = bv.x; acc[r][1] = bv.y; acc[r][2] = bv.z; acc[r][3] = bv.w;
    }

    for (int k = 0; k < DIN; k += 4) {
        float4 w0 = *(const float4*)&W[(size_t)(k + 0) * FOUR_D + j];
        float4 w1 = *(const float4*)&W[(size_t)(k + 1) * FOUR_D + j];
        float4 w2 = *(const float4*)&W[(size_t)(k + 2) * FOUR_D + j];
        float4 w3 = *(const float4*)&W[(size_t)(k + 3) * FOUR_D + j];
#pragma unroll
        for (int r = 0; r < 16; ++r) {
            float4 xv = *(const float4*)&xt[r][k];
            acc[r][0] += xv.x * w0.x + xv.y * w1.x + xv.z * w2.x + xv.w * w3.x;
            acc[r][1] += xv.x * w0.y + xv.y * w1.y + xv.z * w2.y + xv.w * w3.y;
            acc[r][2] += xv.x * w0.z + xv.y * w1.z + xv.z * w2.z + xv.w * w3.z;
            acc[r][3] += xv.x * w0.w + xv.y * w1.w + xv.z * w2.w + xv.w * w3.w;
        }
    }

#pragma unroll
    for (int r = 0; r < 16; ++r) {
        float4 st = make_float4(acc[r][0], acc[r][1], acc[r][2], acc[r][3]);
        *(float4*)&px[((size_t)(rbase + r)) * FOUR_D + j] = st;
    }
}

// 16 named float4 weight registers (R9: compiler remats the loads from L2,
// which is acceptable — they're issued post-B1, overlapped across waves).
#define REP16(M) M(0) M(1) M(2) M(3) M(4) M(5) M(6) M(7) \
                 M(8) M(9) M(10) M(11) M(12) M(13) M(14) M(15)

#define U_DECL(n) float4 u##n;
#define U_LOAD(n) u##n = make_float4(                         \
    Ucol[(size_t)(kbase + 4*(n) + 0) * FOUR_D],               \
    Ucol[(size_t)(kbase + 4*(n) + 1) * FOUR_D],               \
    Ucol[(size_t)(kbase + 4*(n) + 2) * FOUR_D],               \
    Ucol[(size_t)(kbase + 4*(n) + 3) * FOUR_D]);
#define GEMV_STEP(n) {                                        \
    float4 hv = *(const float4*)&h_lds[kbase + 4*(n)];        \
    a0 += hv.x * u##n.x; a1 += hv.y * u##n.y;                 \
    a2 += hv.z * u##n.z; a3 += hv.w * u##n.w; }

// L1-bypassing 8B load: served by the local XCD L2, where same-XCD plain
// stores land. Used ONLY after a one-shot probe proves visibility.
__device__ __forceinline__ unsigned long long load_sc0_u64(const unsigned long long* p) {
    unsigned long long r;
    asm volatile("global_load_dwordx2 %0, %1, off sc0\n\t"
                 "s_waitcnt vmcnt(0)"
                 : "=v"(r) : "v"(p) : "memory");
    return r;
}

// Transposed scan (R9 structure) with XCD-affine fast transport.
// blockIdx = 8j + x: batch = 4x + (j>>3), w = j&7 -> under round-robin
// dispatch all 8 WGs of a batch share XCD x (heuristic only). Producers
// publish to hfast (plain store -> local L2) AND hslow (agent atomic, the
// proven LLC path). Each consumer thread classifies its slot ONCE: first
// exchange observed via hslow, then one sc0 load of hfast decides fastok.
// Fast spins carry a 1024-try cap with permanent demotion -> no hang, no
// per-step spin death; worst case = R9 behavior.
__global__ __launch_bounds__(512, 2) void lstm_scan9(
    const float* __restrict__ px, const float* __restrict__ U,
    float* __restrict__ out,
    unsigned long long* __restrict__ hslow,
    unsigned long long* __restrict__ hfast,
    float* __restrict__ cstate, int t0, int ct)
{
    __shared__ float h_lds[DH];
    __shared__ float red[KSEG][COLS + 1];
    __shared__ float act_s[COLS];

    const int xh = blockIdx.x & 7;     // XCD hint (round-robin heuristic)
    const int j = blockIdx.x >> 3;     // 0..31
    const int b = xh * 4 + (j >> 3);   // batch
    const int w = j & 7;               // WG-within-batch
    const int tid = threadIdx.x;
    const int c = tid & (COLS - 1);    // col within WG: 0..127
    const int seg = tid >> 7;          // 0..3
    const int kbase = seg << 6;        // 0,64,128,192
    const int gg = c >> 5, jj = c & 31;
    const int colg = (gg << 8) + (w << 5) + jj;   // global preact column

    const float* Ucol = U + colg;
    REP16(U_DECL)
    REP16(U_LOAD)

    float c_reg = 0.0f;
    if (tid < DPW) c_reg = cstate[b * DH + (w << 5) + tid];

    bool probed = false, fastok = false;

    for (int tt = 0; tt < ct; ++tt) {
        const int s = t0 + tt + 1;     // computing h_s from h_{s-1}

        // px prefetch (independent of h): issue before the spin
        float pxv = 0.0f;
        if (tid < COLS)
            pxv = px[((size_t)tt * B_SZ + b) * FOUR_D + colg];

        // acquire h_{s-1}: threads 0..255 poll their own dim (tag==step)
        if (tid < DH) {
            if (s == 1) {
                h_lds[tid] = 0.0f;
            } else {
                const unsigned want = (unsigned)(s - 1);
                const size_t off = ((size_t)((s - 1) & 1) * B_SZ + b) * DH + tid;
                unsigned long long v;
                if (!probed) {
                    // proven slow path observes first value
                    do {
                        v = __hip_atomic_load(hslow + off, __ATOMIC_RELAXED,
                                              __HIP_MEMORY_SCOPE_AGENT);
                    } while ((unsigned)(v >> 32) != want);
                    // one-shot classification of the fast transport
                    unsigned long long f = load_sc0_u64(hfast + off);
                    fastok = ((unsigned)(f >> 32) == want);
                    probed = true;
                } else if (fastok) {
                    int tries = 0;
                    for (;;) {
                        v = load_sc0_u64(hfast + off);
                        if ((unsigned)(v >> 32) == want) break;
                        if (++tries > 1024) {      // permanent demotion
                            fastok = false;
                            do {
                                v = __hip_atomic_load(hslow + off, __ATOMIC_RELAXED,
                                                      __HIP_MEMORY_SCOPE_AGENT);
                            } while ((unsigned)(v >> 32) != want);
                            break;
                        }
                    }
                } else {
                    do {
                        v = __hip_atomic_load(hslow + off, __ATOMIC_RELAXED,
                                              __HIP_MEMORY_SCOPE_AGENT);
                    } while ((unsigned)(v >> 32) != want);
                }
                h_lds[tid] = __uint_as_float((unsigned)v);
            }
        }
        __syncthreads();   // B1: h_lds ready

        // GEMV critical path: 64 FMAs, h broadcast from LDS
        float a0 = 0.f, a1 = 0.f, a2 = 0.f, a3 = 0.f;
        REP16(GEMV_STEP)
        red[seg][c] = (a0 + a1) + (a2 + a3);
        __syncthreads();   // B2: partials ready

        if (tid < COLS) {
            float pre = pxv + red[0][tid] + red[1][tid]
                            + red[2][tid] + red[3][tid];
            float a;
            if (tid < 96) {
                a = 1.0f / (1.0f + __expf(-pre));          // i, f, o
            } else {
                float e = __expf(-2.0f * pre);             // g = tanh
                a = 2.0f / (1.0f + e) - 1.0f;
            }
            act_s[tid] = a;
        }
        __syncthreads();   // B3: activations ready

        if (tid < DPW) {
            float ig = act_s[tid];
            float fg = act_s[32 + tid];
            float og = act_s[64 + tid];
            float gv = act_s[96 + tid];
            float cn = fg * c_reg + ig * gv;
            c_reg = cn;
            float ec = __expf(-2.0f * cn);
            float hn = og * (2.0f / (1.0f + ec) - 1.0f);
            const int d = (w << 5) + tid;
            unsigned long long pv =
                ((unsigned long long)(unsigned)s << 32) |
                (unsigned long long)__float_as_uint(hn);
            const size_t poff = ((size_t)(s & 1) * B_SZ + b) * DH + d;
            // fast transport first (local L2), then the proven LLC publish
            *(volatile unsigned long long*)(hfast + poff) = pv;
            __hip_atomic_store(hslow + poff, pv, __ATOMIC_RELAXED,
                               __HIP_MEMORY_SCOPE_AGENT);
            out[((size_t)b * T_SZ + (size_t)(s - 1)) * DH + d] = hn;
        }
        // no trailing barrier: next-iter writers are gated behind next-iter
        // B1/B2/B3 rendezvous (same argument as R4/R9).
    }

    if (tid < DPW) cstate[b * DH + (w << 5) + tid] = c_reg;
}

extern "C" void kernel_launch(void* const* d_in, const int* in_sizes, int n_in,
                              void* d_out, int out_size, void* d_ws, size_t ws_size,
                              hipStream_t stream) {
    const float* x    = (const float*)d_in[0];
    const float* W    = (const float*)d_in[1];
    const float* U    = (const float*)d_in[2];
    const float* bias = (const float*)d_in[3];
    float* out = (float*)d_out;

    // ws layout: cstate 32KB @0 | hslow 128KB @32K | hfast 128KB @160K | px @288K
    float* cstate = (float*)d_ws;
    unsigned long long* hslow = (unsigned long long*)((char*)d_ws + 32 * 1024);
    unsigned long long* hfast = (unsigned long long*)((char*)d_ws + 160 * 1024);
    size_t px_off = 288 * 1024;
    float* pxbuf = (float*)((char*)d_ws + px_off);

    size_t avail = (ws_size > px_off) ? (ws_size - px_off) : 0;
    size_t per_step = (size_t)B_SZ * FOUR_D * sizeof(float);  // 128 KB
    long ct_max = (long)(avail / per_step);
    int CT = (ct_max >= T_SZ) ? T_SZ : (int)ct_max;
    if (CT < 1) CT = 1;

    // zero cstate + hslow + hfast each launch
    int zero_words = (288 * 1024) / 4;
    zero_ws<<<(zero_words + 255) / 256, 256, 0, stream>>>((unsigned int*)d_ws, zero_words);

    for (int t0 = 0; t0 < T_SZ; t0 += CT) {
        int ct = (T_SZ - t0 < CT) ? (T_SZ - t0) : CT;
        int rows = ct * B_SZ;
        px_gemm<<<rows / 16, 256, 0, stream>>>(x, W, bias, pxbuf, t0);
        lstm_scan9<<<B_SZ * NW, 512, 0, stream>>>(
            pxbuf, U, out, hslow, hfast, cstate, t0, ct);
    }
}

// Round 12
// 4612.711 us; speedup vs baseline: 1.5061x; 1.0235x over previous
//
#include <hip/hip_runtime.h>
#include <math.h>

#define B_SZ 32
#define T_SZ 2048
#define DIN 256
#define DH 256
#define FOUR_D 1024

// G=2 batches per group; 16 WGs per group; 512 threads; WG owns 16 dims.
#define NW 16
#define DPW 16
#define COLS 64        // preact cols per WG (4 gates x 16 dims)
#define KSEG 8         // 512 threads = 64 cols x 8 K-segments
#define KLEN 32        // K elements per segment -> 8 float4 weights (remat)

__global__ void zero_ws(unsigned int* p, int n) {
    int i = blockIdx.x * blockDim.x + threadIdx.x;
    if (i < n) p[i] = 0u;
}

// px[r][f] = bias[f] + sum_k x_row(r)[k] * W[k][f];  r = tt*32 + b   (proven)
__global__ __launch_bounds__(256) void px_gemm(
    const float* __restrict__ x, const float* __restrict__ W,
    const float* __restrict__ bias, float* __restrict__ px,
    int t0)
{
    __shared__ float xt[16][DIN];
    const int tid = threadIdx.x;
    const int rbase = blockIdx.x * 16;

    {
        int row = tid >> 4;
        int seg = (tid & 15) * 16;
        int r = rbase + row;
        int bb = r & 31;
        int tt = r >> 5;
        const float4* s4 = (const float4*)(x + ((size_t)bb * T_SZ + (size_t)(t0 + tt)) * DIN + seg);
        float4* dst = (float4*)&xt[row][seg];
        dst[0] = s4[0]; dst[1] = s4[1]; dst[2] = s4[2]; dst[3] = s4[3];
    }
    __syncthreads();

    const int j = tid * 4;
    float4 bv = *(const float4*)&bias[j];
    float acc[16][4];
#pragma unroll
    for (int r = 0; r < 16; ++r) {
        acc[r][0] = bv.x; acc[r][1] = bv.y; acc[r][2] = bv.z; acc[r][3] = bv.w;
    }

    for (int k = 0; k < DIN; k += 4) {
        float4 w0 = *(const float4*)&W[(size_t)(k + 0) * FOUR_D + j];
        float4 w1 = *(const float4*)&W[(size_t)(k + 1) * FOUR_D + j];
        float4 w2 = *(const float4*)&W[(size_t)(k + 2) * FOUR_D + j];
        float4 w3 = *(const float4*)&W[(size_t)(k + 3) * FOUR_D + j];
#pragma unroll
        for (int r = 0; r < 16; ++r) {
            float4 xv = *(const float4*)&xt[r][k];
            acc[r][0] += xv.x * w0.x + xv.y * w1.x + xv.z * w2.x + xv.w * w3.x;
            acc[r][1] += xv.x * w0.y + xv.y * w1.y + xv.z * w2.y + xv.w * w3.y;
            acc[r][2] += xv.x * w0.z + xv.y * w1.z + xv.z * w2.z + xv.w * w3.z;
            acc[r][3] += xv.x * w0.w + xv.y * w1.w + xv.z * w2.w + xv.w * w3.w;
        }
    }

#pragma unroll
    for (int r = 0; r < 16; ++r) {
        float4 st = make_float4(acc[r][0], acc[r][1], acc[r][2], acc[r][3]);
        *(float4*)&px[((size_t)(rbase + r)) * FOUR_D + j] = st;
    }
}

// 8 named float4 weight quads, loaded post-B1 (compiler remats from L2 —
// accepted; each quad now feeds TWO batches, halving the per-CU re-stream).
#define REP8(M) M(0) M(1) M(2) M(3) M(4) M(5) M(6) M(7)

#define U_DECL(n) float4 u##n;
#define U_LOAD(n) u##n = make_float4(                         \
    Ucol[(size_t)(kbase + 4*(n) + 0) * FOUR_D],               \
    Ucol[(size_t)(kbase + 4*(n) + 1) * FOUR_D],               \
    Ucol[(size_t)(kbase + 4*(n) + 2) * FOUR_D],               \
    Ucol[(size_t)(kbase + 4*(n) + 3) * FOUR_D]);
#define GEMV2_STEP(n) {                                       \
    float4 h0 = *(const float4*)&h_lds[0][kbase + 4*(n)];     \
    float4 h1 = *(const float4*)&h_lds[1][kbase + 4*(n)];     \
    a0 += h0.x * u##n.x + h0.y * u##n.y                       \
        + h0.z * u##n.z + h0.w * u##n.w;                      \
    a1 += h1.x * u##n.x + h1.y * u##n.y                       \
        + h1.z * u##n.z + h1.w * u##n.w; }

// Group-batched transposed scan (G=2, R9 skeleton): blockIdx = grp*16 + w;
// group owns batches {2grp, 2grp+1}; WG owns dims [16w,16w+16) for BOTH.
// Poll: proven agent-scope 64-bit tagged atomics, parity dbuf, 256 pollers
// dual-spinning 2 slots. Tail merged (no act_s, no 3rd barrier).
__global__ __launch_bounds__(512, 2) void lstm_scan10(
    const float* __restrict__ px, const float* __restrict__ U,
    float* __restrict__ out, unsigned long long* __restrict__ hbuf,
    float* __restrict__ cstate, int t0, int ct)
{
    __shared__ float h_lds[2][DH];
    __shared__ float red[KSEG][2][COLS + 1];

    const int grp = blockIdx.x >> 4;   // 0..15
    const int w = blockIdx.x & 15;     // 0..15
    const int b0 = grp * 2;            // first batch of pair
    const int tid = threadIdx.x;
    const int c = tid & (COLS - 1);    // col within WG: 0..63
    const int seg = tid >> 6;          // 0..7
    const int kbase = seg << 5;        // 0,32,...,224
    const int gate = c >> 4, jj = c & 15;
    const int colg = (gate << 8) + (w << 4) + jj;   // global preact column
    const float* Ucol = U + colg;

    // cell state: threads 0..31 hold (g = tid>>4, dd = tid&15)
    float c_reg = 0.0f;
    if (tid < 2 * DPW) {
        int g = tid >> 4, dd = tid & 15;
        c_reg = cstate[(b0 + g) * DH + (w << 4) + dd];
    }

    for (int tt = 0; tt < ct; ++tt) {
        const int s = t0 + tt + 1;     // computing h_s from h_{s-1}

        // px prefetch: threads 0..127 cover (g = seg, col c) for both batches
        float pxv = 0.0f;
        if (tid < 2 * COLS)
            pxv = px[((size_t)tt * B_SZ + b0 + seg) * FOUR_D + colg];

        // acquire h_{s-1} for both batches: 256 pollers, dual-slot spin
        if (tid < DH) {
            if (s == 1) {
                h_lds[0][tid] = 0.0f;
                h_lds[1][tid] = 0.0f;
            } else {
                const unsigned want = (unsigned)(s - 1);
                const size_t base = ((size_t)((s - 1) & 1) * B_SZ) * DH;
                const unsigned long long* slotA = hbuf + base + (size_t)b0 * DH + tid;
                const unsigned long long* slotB = hbuf + base + (size_t)(b0 + 1) * DH + tid;
                bool dA = false, dB = false;
                do {
                    if (!dA) {
                        unsigned long long v = __hip_atomic_load(slotA, __ATOMIC_RELAXED,
                                                                 __HIP_MEMORY_SCOPE_AGENT);
                        if ((unsigned)(v >> 32) == want) {
                            h_lds[0][tid] = __uint_as_float((unsigned)v); dA = true;
                        }
                    }
                    if (!dB) {
                        unsigned long long v = __hip_atomic_load(slotB, __ATOMIC_RELAXED,
                                                                 __HIP_MEMORY_SCOPE_AGENT);
                        if ((unsigned)(v >> 32) == want) {
                            h_lds[1][tid] = __uint_as_float((unsigned)v); dB = true;
                        }
                    }
                } while (!(dA && dB));
            }
        }
        __syncthreads();   // B1: h_lds ready (both batches)

        // GEMV: 8 weight quads (remat from L2), each feeding BOTH batches
        float a0 = (seg == 0) ? pxv : 0.0f;   // batch-0 px lands in seg-0 acc
        float a1 = (seg == 1) ? pxv : 0.0f;   // batch-1 px lands in seg-1 acc
        REP8(U_DECL)
        REP8(U_LOAD)
        REP8(GEMV2_STEP)
        red[seg][0][c] = a0;
        red[seg][1][c] = a1;
        __syncthreads();   // B2: partials ready

        // merged tail: 32 threads do gates + cell + publish + out directly
        if (tid < 2 * DPW) {
            int g = tid >> 4, dd = tid & 15;
            float pi = 0.f, pf = 0.f, po = 0.f, pg = 0.f;
#pragma unroll
            for (int ks = 0; ks < KSEG; ++ks) {
                pi += red[ks][g][dd];
                pf += red[ks][g][16 + dd];
                po += red[ks][g][32 + dd];
                pg += red[ks][g][48 + dd];
            }
            float ig = 1.0f / (1.0f + __expf(-pi));
            float fg = 1.0f / (1.0f + __expf(-pf));
            float og = 1.0f / (1.0f + __expf(-po));
            float eg = __expf(-2.0f * pg);
            float gv = 2.0f / (1.0f + eg) - 1.0f;
            float cn = fg * c_reg + ig * gv;
            c_reg = cn;
            float ec = __expf(-2.0f * cn);
            float hn = og * (2.0f / (1.0f + ec) - 1.0f);
            const int d = (w << 4) + dd;
            // publish FIRST (critical path), out-store after
            unsigned long long pv =
                ((unsigned long long)(unsigned)s << 32) |
                (unsigned long long)__float_as_uint(hn);
            __hip_atomic_store(hbuf + (((size_t)(s & 1) * B_SZ + b0 + g) * DH + d),
                               pv, __ATOMIC_RELAXED, __HIP_MEMORY_SCOPE_AGENT);
            out[((size_t)(b0 + g) * T_SZ + (size_t)(s - 1)) * DH + d] = hn;
        }
        // no trailing barrier: red rewrite gated behind B1_{t+1} (tail threads
        // must arrive there); h_lds rewrite gated behind B2_t passage.
    }

    if (tid < 2 * DPW) {
        int g = tid >> 4, dd = tid & 15;
        cstate[(b0 + g) * DH + (w << 4) + dd] = c_reg;
    }
}

extern "C" void kernel_launch(void* const* d_in, const int* in_sizes, int n_in,
                              void* d_out, int out_size, void* d_ws, size_t ws_size,
                              hipStream_t stream) {
    const float* x    = (const float*)d_in[0];
    const float* W    = (const float*)d_in[1];
    const float* U    = (const float*)d_in[2];
    const float* bias = (const float*)d_in[3];
    float* out = (float*)d_out;

    // ws layout: cstate 32KB @0 | hbuf 128KB @32K | pxbuf @160K
    float* cstate = (float*)d_ws;
    unsigned long long* hbuf = (unsigned long long*)((char*)d_ws + 32 * 1024);
    size_t px_off = 160 * 1024;
    float* pxbuf = (float*)((char*)d_ws + px_off);

    size_t avail = (ws_size > px_off) ? (ws_size - px_off) : 0;
    size_t per_step = (size_t)B_SZ * FOUR_D * sizeof(float);  // 128 KB
    long ct_max = (long)(avail / per_step);
    int CT = (ct_max >= T_SZ) ? T_SZ : (int)ct_max;
    if (CT < 1) CT = 1;

    // zero cstate + hbuf each launch
    int zero_words = (160 * 1024) / 4;
    zero_ws<<<(zero_words + 255) / 256, 256, 0, stream>>>((unsigned int*)d_ws, zero_words);

    for (int t0 = 0; t0 < T_SZ; t0 += CT) {
        int ct = (T_SZ - t0 < CT) ? (T_SZ - t0) : CT;
        int rows = ct * B_SZ;
        px_gemm<<<rows / 16, 256, 0, stream>>>(x, W, bias, pxbuf, t0);
        lstm_scan10<<<16 * NW, 512, 0, stream>>>(pxbuf, U, out, hbuf, cstate, t0, ct);
    }
}